// Round 1
// baseline (5041.223 us; speedup 1.0000x reference)
//
#include <hip/hip_runtime.h>

typedef unsigned int u32;
typedef unsigned short u16;
typedef __attribute__((ext_vector_type(8))) short bf16x8;   // 8 bf16 = 4 VGPRs (MFMA A/B frag)
typedef __attribute__((ext_vector_type(4))) float f32x4;    // MFMA C/D frag

#define T_STEPS 512
#define NOUT_H  16777216ull   // T*B*H
// workspace byte offsets
#define WS_FLAGS  256ull                       // 64 flags, 64B apart (4KB)
#define WS_BIAS   8192ull                      // f32[2048]
#define WS_HBUF0  16384ull                     // 64KB (swizzled h, parity 0)
#define WS_HBUF1  81920ull                     // 64KB (parity 1)
#define WS_WXS    147456ull                    // 2MB swizzled Wx (bf16)
#define WS_WHS    2244608ull                   // 2MB swizzled Wh (bf16)
#define WS_XC     4341760ull                   // 32MB X as bf16
#define WS_XW     37896192ull                  // XW: 268MB f32 or 134MB bf16

__device__ __forceinline__ u16 f2bf(float f) {
  u32 u = __builtin_bit_cast(u32, f);
  u32 r = (u + 0x7fffu + ((u >> 16) & 1u)) >> 16;
  return (u16)r;
}
__device__ __forceinline__ float bf2f(u16 h) {
  u32 u = ((u32)h) << 16;
  return __builtin_bit_cast(float, u);
}
__device__ __forceinline__ float sigf(float x) { return 1.0f / (1.0f + expf(-x)); }

// ---------------- K0: dtype detect + zero flags/hbufs ----------------
__global__ void k_detect(const u32* __restrict__ x, u32* __restrict__ ws) {
  __shared__ int cnt;
  if (threadIdx.x == 0) cnt = 0;
  __syncthreads();
  int good = 0;
  for (int i = 0; i < 4; ++i) {
    u32 v = x[threadIdx.x * 4 + i];
    u32 e = (v >> 7) & 0xff;          // low 16 bits interpreted as bf16: exponent field
    good += (e >= 100 && e <= 140) ? 1 : 0;
  }
  atomicAdd(&cnt, good);
  __syncthreads();
  if (threadIdx.x == 0) ws[0] = (cnt >= 512) ? 1u : 0u;  // 1 = bf16 inputs, 0 = f32 inputs
  u32* flags = ws + WS_FLAGS / 4;
  for (int i = threadIdx.x; i < 1024; i += 256) flags[i] = 0;
  u32* hb = ws + WS_HBUF0 / 4;
  for (int i = threadIdx.x; i < (131072 / 4); i += 256) hb[i] = 0;
}

// ---------------- K1: X f32 -> bf16 (no-op in bf16 mode) ----------------
__global__ void k_convx(const u32* __restrict__ ws, const void* __restrict__ xin,
                        u16* __restrict__ xc) {
  if (ws[0]) return;  // bf16 mode: K3 reads input directly
  int idx = blockIdx.x * 256 + threadIdx.x;  // 4 elements each, 16777216 total
  float4 f = ((const float4*)xin)[idx];
  ushort4 o;
  o.x = f2bf(f.x); o.y = f2bf(f.y); o.z = f2bf(f.z); o.w = f2bf(f.w);
  ((ushort4*)xc)[idx] = o;
}

// ---------------- K2: swizzle W into MFMA-fragment-linear chunks + bias ----------------
// chunk(…,ks,q,n) 16B holds 8 bf16 along k: k = ks*32 + q*8 + j. Lane-linear: lane = q*16+n.
__global__ void k_prepw(u32* __restrict__ ws,
                        const void* Wf, const void* Wi, const void* Wg, const void* Wo,
                        const void* bfp, const void* bip, const void* bgp, const void* bop) {
  u32 mode = ws[0];
  const void* Wp[4] = {Wf, Wi, Wg, Wo};
  int tid = blockIdx.x * 256 + threadIdx.x;   // 262144 threads
  u16* wxs = (u16*)((char*)ws + WS_WXS);
  u16* whs = (u16*)((char*)ws + WS_WHS);
  int c, iswh;
  if (tid < 131072) { c = tid; iswh = 0; } else { c = tid - 131072; iswh = 1; }
  int n = c & 15, q = (c >> 4) & 3, ks = (c >> 6) & 15;
  int g, j, krow0;
  if (!iswh) {                       // Wx chunks: [ntg(128)][ks][q][n]
    int ntg = c >> 10;
    int col = ntg * 16 + n; g = col >> 9; j = col & 511; krow0 = 0;
  } else {                           // Wh chunks: [w(64)][nt(2)][ks][q][n], col = g*512 + w*8 + jj
    int nt = (c >> 10) & 1, w = c >> 11;
    int cl = nt * 16 + n; g = cl >> 3; j = w * 8 + (cl & 7); krow0 = 512;
  }
  int kbase = krow0 + ks * 32 + q * 8;
  u16 vals[8];
  if (mode) {
    const u16* Ws = (const u16*)Wp[g];
    for (int jj = 0; jj < 8; ++jj) vals[jj] = Ws[(size_t)(kbase + jj) * 512 + j];
  } else {
    const float* Ws = (const float*)Wp[g];
    for (int jj = 0; jj < 8; ++jj) vals[jj] = f2bf(Ws[(size_t)(kbase + jj) * 512 + j]);
  }
  uint4 pk;
  pk.x = (u32)vals[0] | ((u32)vals[1] << 16);
  pk.y = (u32)vals[2] | ((u32)vals[3] << 16);
  pk.z = (u32)vals[4] | ((u32)vals[5] << 16);
  pk.w = (u32)vals[6] | ((u32)vals[7] << 16);
  ((uint4*)(iswh ? whs : wxs))[c] = pk;
  if (tid < 2048) {
    const void* bp[4] = {bfp, bip, bgp, bop};
    int bg = tid >> 9, bj = tid & 511;
    float* bias = (float*)((char*)ws + WS_BIAS);
    bias[tid] = mode ? bf2f(((const u16*)bp[bg])[bj]) : ((const float*)bp[bg])[bj];
  }
}

// ---------------- K3: XW = X @ Wx + b, stored in K4 C-frag-linear layout ----------------
// grid 8192: mg = bid>>4 (timestep t, 64 rows), ng = bid&15 (128 cols). Wave v: 4 mtiles x 2 ntiles.
__global__ __launch_bounds__(256) void k_xw(u32* __restrict__ ws, const void* __restrict__ xorig,
                                            int xwf32) {
  u32 mode = ws[0];
  const u16* xc = mode ? (const u16*)xorig : (const u16*)((char*)ws + WS_XC);
  const u16* wxs = (const u16*)((char*)ws + WS_WXS);
  const float* bias = (const float*)((char*)ws + WS_BIAS);
  char* xwp = (char*)ws + WS_XW;
  int v = threadIdx.x >> 6, lane = threadIdx.x & 63, q = lane >> 4, n = lane & 15;
  int mg = blockIdx.x >> 4, ng = blockIdx.x & 15;
  f32x4 acc[4][2] = {};
  for (int ks = 0; ks < 16; ++ks) {
    bf16x8 a[4];
#pragma unroll
    for (int mt = 0; mt < 4; ++mt)
      a[mt] = *(const bf16x8*)(xc + ((size_t)(mg * 64 + mt * 16 + n) * 512 + ks * 32 + q * 8));
#pragma unroll
    for (int jb = 0; jb < 2; ++jb) {
      int ntg = ng * 8 + v * 2 + jb;
      bf16x8 b = *(const bf16x8*)(wxs + ((size_t)(ntg * 16 + ks) * 64 + lane) * 8);
#pragma unroll
      for (int mt = 0; mt < 4; ++mt)
        acc[mt][jb] = __builtin_amdgcn_mfma_f32_16x16x32_bf16(a[mt], b, acc[mt][jb], 0, 0, 0);
    }
  }
#pragma unroll
  for (int jb = 0; jb < 2; ++jb) {
    int ntg = ng * 8 + v * 2 + jb;
    int col = ntg * 16 + n;
    float bv = bias[col];
    int g = col >> 9, j = col & 511;
    int w = j >> 3, cl = g * 8 + (j & 7);
    int nt4 = cl >> 4, n4 = cl & 15;
#pragma unroll
    for (int mt = 0; mt < 4; ++mt) {
      // XWswz layout: [t][v4(4)][w(64)][nt(2)][lane(64)][r(4)] ; v4 = mt, lane = q*16+n4
      size_t base = ((((size_t)mg * 4 + mt) * 64 + w) * 2 + nt4) * 64 + q * 16 + n4;
      f32x4 vec = acc[mt][jb];
      vec[0] += bv; vec[1] += bv; vec[2] += bv; vec[3] += bv;
      if (xwf32) {
        ((f32x4*)xwp)[base] = vec;
      } else {
        ushort4 o;
        o.x = f2bf(vec[0]); o.y = f2bf(vec[1]); o.z = f2bf(vec[2]); o.w = f2bf(vec[3]);
        ((ushort4*)xwp)[base] = o;
      }
    }
  }
}

// ---------------- K4: persistent recurrent kernel ----------------
// 64 WGs x 256. WG w owns h-cols [w*8, w*8+8) (=> gate cols g*512+w*8+jj, g=0..3).
// Wave v owns batch rows [v*16, v*16+16). Wh slice lives in registers (bfr). c-state in registers.
// h double-buffered in global, fragment-linear; per-producer monotonic flags for sync.
__global__ __launch_bounds__(256, 1) void k_rec(u32* __restrict__ ws, void* __restrict__ out,
                                                int xwf32) {
  __shared__ float gbuf[4 * 16 * 33];              // per-wave 16 rows x 32 gates, stride 33
  __shared__ __align__(16) u16 houtbuf[64 * 8];    // h slice bf16, rows x 8 cols
  u32 mode = ws[0];
  u32* flags = ws + WS_FLAGS / 4;
  const u16* whs = (const u16*)((char*)ws + WS_WHS);
  u16* hb0 = (u16*)((char*)ws + WS_HBUF0);
  u16* hb1 = (u16*)((char*)ws + WS_HBUF1);
  const char* xwp = (const char*)ws + WS_XW;
  int w = blockIdx.x, tid = threadIdx.x, v = tid >> 6, lane = tid & 63;
  int q = lane >> 4, n = lane & 15;

  // Wh fragments -> registers (2 ntiles x 16 ksteps x 16B); ~128 VGPRs, 1 wave/SIMD budget is 512.
  bf16x8 bfr[2][16];
#pragma unroll
  for (int nt = 0; nt < 2; ++nt)
#pragma unroll
    for (int ks = 0; ks < 16; ++ks)
      bfr[nt][ks] = *(const bf16x8*)(whs + ((size_t)w * 2048 + nt * 1024 + ks * 64 + lane) * 8);

  float creg[2] = {0.f, 0.f};  // c-state: item (it*64+lane) -> (b = v*16 + item>>3, jj = item&7)
  float* gb = &gbuf[v * 16 * 33];

  for (int t = 0; t < T_STEPS; ++t) {
    // XW prefetch (no recurrence dependency -> issue before spin)
    f32x4 xw0, xw1;
    {
      size_t b0 = ((((size_t)t * 4 + v) * 64 + w) * 2 + 0) * 64 + lane;
      if (xwf32) {
        xw0 = ((const f32x4*)xwp)[b0];
        xw1 = ((const f32x4*)xwp)[b0 + 64];
      } else {
        ushort4 a0 = ((const ushort4*)xwp)[b0];
        ushort4 a1 = ((const ushort4*)xwp)[b0 + 64];
        xw0[0] = bf2f(a0.x); xw0[1] = bf2f(a0.y); xw0[2] = bf2f(a0.z); xw0[3] = bf2f(a0.w);
        xw1[0] = bf2f(a1.x); xw1[1] = bf2f(a1.y); xw1[2] = bf2f(a1.z); xw1[3] = bf2f(a1.w);
      }
    }
    // wait for all 64 producers to have published step t (t=0 trivially passes; hbuf0 zeroed)
    {
      u32 need = (u32)t;
      while (true) {
        u32 fv = __hip_atomic_load(&flags[lane * 16], __ATOMIC_RELAXED, __HIP_MEMORY_SCOPE_AGENT);
        if (__all((int)(fv >= need))) break;
        __builtin_amdgcn_s_sleep(2);
      }
      __threadfence();  // acquire: make producers' h stores visible
    }
    const u16* hcur = (t & 1) ? hb1 : hb0;
    u16* hnxt = (t & 1) ? hb0 : hb1;

    f32x4 acc0 = xw0, acc1 = xw1;
#pragma unroll
    for (int ks = 0; ks < 16; ++ks) {
      bf16x8 a = *(const bf16x8*)(hcur + ((size_t)(v * 16 + ks) * 64 + lane) * 8);
      acc0 = __builtin_amdgcn_mfma_f32_16x16x32_bf16(a, bfr[0][ks], acc0, 0, 0, 0);
      acc1 = __builtin_amdgcn_mfma_f32_16x16x32_bf16(a, bfr[1][ks], acc1, 0, 0, 0);
    }
    // gates -> LDS (cross-lane shuffle within wave); C/D: row = q*4+r, col = lane&15
#pragma unroll
    for (int r = 0; r < 4; ++r) {
      gb[(q * 4 + r) * 33 + n] = acc0[r];
      gb[(q * 4 + r) * 33 + 16 + n] = acc1[r];
    }
#pragma unroll
    for (int it = 0; it < 2; ++it) {
      int item = it * 64 + lane, r16 = item >> 3, jj = item & 7, b = v * 16 + r16;
      float zf = gb[r16 * 33 + jj];
      float zi = gb[r16 * 33 + 8 + jj];
      float zg = gb[r16 * 33 + 16 + jj];
      float zo = gb[r16 * 33 + 24 + jj];
      float fg = sigf(zf), ig = sigf(zi), gg = tanhf(zg), og = sigf(zo);
      float cnew = fg * creg[it] + ig * gg;
      float hnew = og * tanhf(cnew);
      creg[it] = cnew;
      u16 h16 = f2bf(hnew);
      houtbuf[b * 8 + jj] = h16;
      size_t oi = ((size_t)t * 64 + b) * 512 + w * 8 + jj;
      if (mode) ((u16*)out)[oi] = h16; else ((float*)out)[oi] = hnew;
      if (t == T_STEPS - 1) {
        size_t hx = NOUT_H + (size_t)b * 512 + w * 8 + jj;
        if (mode) { ((u16*)out)[hx] = h16; ((u16*)out)[hx + 32768] = f2bf(cnew); }
        else      { ((float*)out)[hx] = hnew; ((float*)out)[hx + 32768] = cnew; }
      }
    }
    // publish h slice: wave v writes chunks (mt=v, ks=w>>2, q=w&3, n=0..15), one 16B store/lane
    if (lane < 16) {
      uint4 val = *(const uint4*)&houtbuf[(v * 16 + lane) * 8];
      size_t ci = (((size_t)v * 16 + (w >> 2)) * 4 + (w & 3)) * 16 + lane;
      *(uint4*)(hnxt + ci * 8) = val;
    }
    __syncthreads();  // drain all waves' publish stores (vmcnt(0) before s_barrier)
    if (tid == 0) {
      __threadfence();  // release: push h to agent-visible level
      __hip_atomic_store(&flags[w * 16], (u32)(t + 1), __ATOMIC_RELAXED, __HIP_MEMORY_SCOPE_AGENT);
    }
  }
}

extern "C" void kernel_launch(void* const* d_in, const int* in_sizes, int n_in,
                              void* d_out, int out_size, void* d_ws, size_t ws_size,
                              hipStream_t stream) {
  const void* X = d_in[0];
  u32* ws = (u32*)d_ws;
  // f32 XW needs WS_XW + 268MB; otherwise store XW as bf16
  int xwf32 = (ws_size >= (size_t)(WS_XW + 268435456ull + 1024ull)) ? 1 : 0;

  k_detect<<<1, 256, 0, stream>>>((const u32*)X, ws);
  k_convx<<<16384, 256, 0, stream>>>(ws, X, (u16*)((char*)d_ws + WS_XC));
  k_prepw<<<1024, 256, 0, stream>>>(ws, d_in[1], d_in[3], d_in[5], d_in[7],
                                    d_in[2], d_in[4], d_in[6], d_in[8]);
  k_xw<<<8192, 256, 0, stream>>>(ws, X, xwf32);
  k_rec<<<64, 256, 0, stream>>>(ws, d_out, xwf32);
}

// Round 3
// 2315.856 us; speedup vs baseline: 2.1768x; 2.1768x over previous
//
#include <hip/hip_runtime.h>

typedef unsigned int u32;
typedef unsigned short u16;
typedef __attribute__((ext_vector_type(8))) short bf16x8;   // 8 bf16 = 4 VGPRs (MFMA A/B frag)
typedef __attribute__((ext_vector_type(4))) float f32x4;    // MFMA C/D frag

#define T_STEPS 512
#define NOUT_H  16777216ull   // T*B*H
// workspace byte offsets
#define WS_FLAGS  256ull                       // 256 u32 flags (per producer-wave)
#define WS_BIAS   8192ull                      // f32[2048]
#define WS_HBUF0  16384ull                     // 64KB (swizzled h, parity 0)
#define WS_HBUF1  81920ull                     // 64KB (parity 1)
#define WS_WXS    147456ull                    // 2MB swizzled Wx (bf16)
#define WS_WHS    2244608ull                   // 2MB swizzled Wh (bf16)
#define WS_XC     4341760ull                   // 32MB X as bf16
#define WS_XW     37896192ull                  // XW: 268MB f32 or 134MB bf16

__device__ __forceinline__ u16 f2bf(float f) {
  u32 u = __builtin_bit_cast(u32, f);
  u32 r = (u + 0x7fffu + ((u >> 16) & 1u)) >> 16;
  return (u16)r;
}
__device__ __forceinline__ float bf2f(u16 h) {
  u32 u = ((u32)h) << 16;
  return __builtin_bit_cast(float, u);
}
__device__ __forceinline__ float sigf(float x) {
  return __builtin_amdgcn_rcpf(1.0f + __expf(-x));
}
__device__ __forceinline__ float tanh_fast(float x) {
  float xc = fminf(15.0f, fmaxf(-15.0f, x));
  float e = __expf(2.0f * xc);
  return (e - 1.0f) * __builtin_amdgcn_rcpf(e + 1.0f);
}

// ---------------- K0: dtype detect + zero flags/hbufs ----------------
__global__ void k_detect(const u32* __restrict__ x, u32* __restrict__ ws) {
  __shared__ int cnt;
  if (threadIdx.x == 0) cnt = 0;
  __syncthreads();
  int good = 0;
  for (int i = 0; i < 4; ++i) {
    u32 v = x[threadIdx.x * 4 + i];
    u32 e = (v >> 7) & 0xff;          // low 16 bits interpreted as bf16: exponent field
    good += (e >= 100 && e <= 140) ? 1 : 0;
  }
  atomicAdd(&cnt, good);
  __syncthreads();
  if (threadIdx.x == 0) ws[0] = (cnt >= 512) ? 1u : 0u;  // 1 = bf16 inputs, 0 = f32 inputs
  u32* flags = ws + WS_FLAGS / 4;
  for (int i = threadIdx.x; i < 1024; i += 256) flags[i] = 0;
  u32* hb = ws + WS_HBUF0 / 4;
  for (int i = threadIdx.x; i < (131072 / 4); i += 256) hb[i] = 0;
}

// ---------------- K1: X f32 -> bf16 (no-op in bf16 mode) ----------------
__global__ void k_convx(const u32* __restrict__ ws, const void* __restrict__ xin,
                        u16* __restrict__ xc) {
  if (ws[0]) return;  // bf16 mode: K3 reads input directly
  int idx = blockIdx.x * 256 + threadIdx.x;  // 4 elements each, 16777216 total
  float4 f = ((const float4*)xin)[idx];
  ushort4 o;
  o.x = f2bf(f.x); o.y = f2bf(f.y); o.z = f2bf(f.z); o.w = f2bf(f.w);
  ((ushort4*)xc)[idx] = o;
}

// ---------------- K2: swizzle W into MFMA-fragment-linear chunks + bias ----------------
__global__ void k_prepw(u32* __restrict__ ws,
                        const void* Wf, const void* Wi, const void* Wg, const void* Wo,
                        const void* bfp, const void* bip, const void* bgp, const void* bop) {
  u32 mode = ws[0];
  const void* Wp[4] = {Wf, Wi, Wg, Wo};
  int tid = blockIdx.x * 256 + threadIdx.x;   // 262144 threads
  u16* wxs = (u16*)((char*)ws + WS_WXS);
  u16* whs = (u16*)((char*)ws + WS_WHS);
  int c, iswh;
  if (tid < 131072) { c = tid; iswh = 0; } else { c = tid - 131072; iswh = 1; }
  int n = c & 15, q = (c >> 4) & 3, ks = (c >> 6) & 15;
  int g, j, krow0;
  if (!iswh) {                       // Wx chunks: [ntg(128)][ks][q][n]
    int ntg = c >> 10;
    int col = ntg * 16 + n; g = col >> 9; j = col & 511; krow0 = 0;
  } else {                           // Wh chunks: [w(64)][nt(2)][ks][q][n], col = g*512 + w*8 + jj
    int nt = (c >> 10) & 1, w = c >> 11;
    int cl = nt * 16 + n; g = cl >> 3; j = w * 8 + (cl & 7); krow0 = 512;
  }
  int kbase = krow0 + ks * 32 + q * 8;
  u16 vals[8];
  if (mode) {
    const u16* Ws = (const u16*)Wp[g];
    for (int jj = 0; jj < 8; ++jj) vals[jj] = Ws[(size_t)(kbase + jj) * 512 + j];
  } else {
    const float* Ws = (const float*)Wp[g];
    for (int jj = 0; jj < 8; ++jj) vals[jj] = f2bf(Ws[(size_t)(kbase + jj) * 512 + j]);
  }
  uint4 pk;
  pk.x = (u32)vals[0] | ((u32)vals[1] << 16);
  pk.y = (u32)vals[2] | ((u32)vals[3] << 16);
  pk.z = (u32)vals[4] | ((u32)vals[5] << 16);
  pk.w = (u32)vals[6] | ((u32)vals[7] << 16);
  ((uint4*)(iswh ? whs : wxs))[c] = pk;
  if (tid < 2048) {
    const void* bp[4] = {bfp, bip, bgp, bop};
    int bg = tid >> 9, bj = tid & 511;
    float* bias = (float*)((char*)ws + WS_BIAS);
    bias[tid] = mode ? bf2f(((const u16*)bp[bg])[bj]) : ((const float*)bp[bg])[bj];
  }
}

// ---------------- K3: XW = X @ Wx + b, stored in K4 C-frag-linear layout ----------------
__global__ __launch_bounds__(256) void k_xw(u32* __restrict__ ws, const void* __restrict__ xorig,
                                            int xwf32) {
  u32 mode = ws[0];
  const u16* xc = mode ? (const u16*)xorig : (const u16*)((char*)ws + WS_XC);
  const u16* wxs = (const u16*)((char*)ws + WS_WXS);
  const float* bias = (const float*)((char*)ws + WS_BIAS);
  char* xwp = (char*)ws + WS_XW;
  int v = threadIdx.x >> 6, lane = threadIdx.x & 63, q = lane >> 4, n = lane & 15;
  int mg = blockIdx.x >> 4, ng = blockIdx.x & 15;
  f32x4 acc[4][2] = {};
  for (int ks = 0; ks < 16; ++ks) {
    bf16x8 a[4];
#pragma unroll
    for (int mt = 0; mt < 4; ++mt)
      a[mt] = *(const bf16x8*)(xc + ((size_t)(mg * 64 + mt * 16 + n) * 512 + ks * 32 + q * 8));
#pragma unroll
    for (int jb = 0; jb < 2; ++jb) {
      int ntg = ng * 8 + v * 2 + jb;
      bf16x8 b = *(const bf16x8*)(wxs + ((size_t)(ntg * 16 + ks) * 64 + lane) * 8);
#pragma unroll
      for (int mt = 0; mt < 4; ++mt)
        acc[mt][jb] = __builtin_amdgcn_mfma_f32_16x16x32_bf16(a[mt], b, acc[mt][jb], 0, 0, 0);
    }
  }
#pragma unroll
  for (int jb = 0; jb < 2; ++jb) {
    int ntg = ng * 8 + v * 2 + jb;
    int col = ntg * 16 + n;
    float bv = bias[col];
    int g = col >> 9, j = col & 511;
    int w = j >> 3, cl = g * 8 + (j & 7);
    int nt4 = cl >> 4, n4 = cl & 15;
#pragma unroll
    for (int mt = 0; mt < 4; ++mt) {
      // XWswz layout: [t][v4(4)][w(64)][nt(2)][lane(64)][r(4)] ; v4 = mt, lane = q*16+n4
      size_t base = ((((size_t)mg * 4 + mt) * 64 + w) * 2 + nt4) * 64 + q * 16 + n4;
      f32x4 vec = acc[mt][jb];
      vec[0] += bv; vec[1] += bv; vec[2] += bv; vec[3] += bv;
      if (xwf32) {
        ((f32x4*)xwp)[base] = vec;
      } else {
        ushort4 o;
        o.x = f2bf(vec[0]); o.y = f2bf(vec[1]); o.z = f2bf(vec[2]); o.w = f2bf(vec[3]);
        ((ushort4*)xwp)[base] = o;
      }
    }
  }
}

// ---------------- K4: persistent recurrent kernel (fence-free, per-wave flags) ----------------
// 64 WGs x 256. WG w owns h-cols [w*8, w*8+8). Wave v owns batch rows [v*16, v*16+16).
// Wh slice in LDS. h double-buffered in global (fragment-linear), published with
// device-coherent (sc0 sc1) stores; per-WAVE monotonic flags; no fences, no __syncthreads in loop.
// Backpressure: wave raises flag t+1 only after reading ALL of h(t), so no producer at step t+1
// can overwrite buffer parity t&1 before every wave consumed it.
__global__ __launch_bounds__(256, 1) void k_rec(u32* __restrict__ ws, void* __restrict__ out,
                                                int xwf32) {
  __shared__ __align__(16) u16 whlds[16384];       // 32KB: this WG's Wh slice
  __shared__ float gbuf[4 * 16 * 33];              // per-wave 16 rows x 32 gates, stride 33
  __shared__ __align__(16) u16 houtbuf[64 * 8];    // h slice bf16, rows x 8 cols (per-wave region)
  u32 mode = ws[0];
  u32* flags = ws + WS_FLAGS / 4;
  const u16* whs = (const u16*)((char*)ws + WS_WHS);
  char* hb0 = (char*)ws + WS_HBUF0;
  char* hb1 = (char*)ws + WS_HBUF1;
  const char* xwp = (const char*)ws + WS_XW;
  int w = blockIdx.x, tid = threadIdx.x, v = tid >> 6, lane = tid & 63;
  int q = lane >> 4, n = lane & 15;

  // preload Wh slice -> LDS (one-time)
  {
    const uint4* src = (const uint4*)(whs + (size_t)w * 16384);
    uint4* dst = (uint4*)whlds;
    for (int i = tid; i < 2048; i += 256) dst[i] = src[i];
  }
  __syncthreads();

  float creg[2] = {0.f, 0.f};
  float* gb = &gbuf[v * 16 * 33];
  const u32* fp = flags + lane * 4;                // this lane polls producers 4*lane..4*lane+3

  for (int t = 0; t < T_STEPS; ++t) {
    // ---- XW prefetch (no recurrence dependency; overlaps poll) ----
    f32x4 xw0, xw1;
    {
      size_t b0 = ((((size_t)t * 4 + v) * 64 + w) * 2 + 0) * 64 + lane;
      if (xwf32) {
        xw0 = ((const f32x4*)xwp)[b0];
        xw1 = ((const f32x4*)xwp)[b0 + 64];
      } else {
        ushort4 a0 = ((const ushort4*)xwp)[b0];
        ushort4 a1 = ((const ushort4*)xwp)[b0 + 64];
        xw0[0] = bf2f(a0.x); xw0[1] = bf2f(a0.y); xw0[2] = bf2f(a0.z); xw0[3] = bf2f(a0.w);
        xw1[0] = bf2f(a1.x); xw1[1] = bf2f(a1.y); xw1[2] = bf2f(a1.z); xw1[3] = bf2f(a1.w);
      }
    }
    // ---- poll: all 256 producer waves published step t (coherent load, no fence) ----
    {
      u32 need = (u32)t;
      while (true) {
        uint4 f;
        asm volatile("global_load_dwordx4 %0, %1, off sc0 sc1\n\ts_waitcnt vmcnt(0)"
                     : "=&v"(f) : "v"(fp) : "memory");
        int ok = (f.x >= need) && (f.y >= need) && (f.z >= need) && (f.w >= need);
        if (__all(ok)) break;
        __builtin_amdgcn_s_sleep(1);
      }
    }
    const char* hcur = (t & 1) ? hb1 : hb0;
    char* hnxt = (t & 1) ? hb0 : hb1;

    // ---- coherent h loads: 16 x 16B per lane, single asm block ending in vmcnt(0) ----
    uint4 ha[16];
    {
      const char* b0 = hcur + (size_t)v * 16384 + (size_t)lane * 16;
      const char* b4 = b0 + 4096;
      const char* b8 = b0 + 8192;
      const char* b12 = b0 + 12288;
      asm volatile(
          "global_load_dwordx4 %0, %16, off sc0 sc1\n\t"
          "global_load_dwordx4 %1, %16, off offset:1024 sc0 sc1\n\t"
          "global_load_dwordx4 %2, %16, off offset:2048 sc0 sc1\n\t"
          "global_load_dwordx4 %3, %16, off offset:3072 sc0 sc1\n\t"
          "global_load_dwordx4 %4, %17, off sc0 sc1\n\t"
          "global_load_dwordx4 %5, %17, off offset:1024 sc0 sc1\n\t"
          "global_load_dwordx4 %6, %17, off offset:2048 sc0 sc1\n\t"
          "global_load_dwordx4 %7, %17, off offset:3072 sc0 sc1\n\t"
          "global_load_dwordx4 %8, %18, off sc0 sc1\n\t"
          "global_load_dwordx4 %9, %18, off offset:1024 sc0 sc1\n\t"
          "global_load_dwordx4 %10, %18, off offset:2048 sc0 sc1\n\t"
          "global_load_dwordx4 %11, %18, off offset:3072 sc0 sc1\n\t"
          "global_load_dwordx4 %12, %19, off sc0 sc1\n\t"
          "global_load_dwordx4 %13, %19, off offset:1024 sc0 sc1\n\t"
          "global_load_dwordx4 %14, %19, off offset:2048 sc0 sc1\n\t"
          "global_load_dwordx4 %15, %19, off offset:3072 sc0 sc1\n\t"
          "s_waitcnt vmcnt(0)"
          : "=&v"(ha[0]), "=&v"(ha[1]), "=&v"(ha[2]), "=&v"(ha[3]),
            "=&v"(ha[4]), "=&v"(ha[5]), "=&v"(ha[6]), "=&v"(ha[7]),
            "=&v"(ha[8]), "=&v"(ha[9]), "=&v"(ha[10]), "=&v"(ha[11]),
            "=&v"(ha[12]), "=&v"(ha[13]), "=&v"(ha[14]), "=&v"(ha[15])
          : "v"(b0), "v"(b4), "v"(b8), "v"(b12)
          : "memory");
    }

    // ---- MFMA: gates = h @ Wh (+xw) ----
    f32x4 acc0 = xw0, acc1 = xw1;
#pragma unroll
    for (int ks = 0; ks < 16; ++ks) {
      bf16x8 a = __builtin_bit_cast(bf16x8, ha[ks]);
      bf16x8 bb0 = *(const bf16x8*)&whlds[(ks * 64 + lane) * 8];
      bf16x8 bb1 = *(const bf16x8*)&whlds[((16 + ks) * 64 + lane) * 8];
      acc0 = __builtin_amdgcn_mfma_f32_16x16x32_bf16(a, bb0, acc0, 0, 0, 0);
      acc1 = __builtin_amdgcn_mfma_f32_16x16x32_bf16(a, bb1, acc1, 0, 0, 0);
    }
    // ---- gates -> LDS (wave-local shuffle); C/D: row = q*4+r, col = lane&15 ----
#pragma unroll
    for (int r = 0; r < 4; ++r) {
      gb[(q * 4 + r) * 33 + n] = acc0[r];
      gb[(q * 4 + r) * 33 + 16 + n] = acc1[r];
    }
    // ---- elementwise (2 items/thread), wave-local ----
    float hnew_s[2], cnew_s[2];
    int bidx[2];
#pragma unroll
    for (int it = 0; it < 2; ++it) {
      int item = it * 64 + lane, r16 = item >> 3, jj = item & 7, b = v * 16 + r16;
      float zf = gb[r16 * 33 + jj];
      float zi = gb[r16 * 33 + 8 + jj];
      float zg = gb[r16 * 33 + 16 + jj];
      float zo = gb[r16 * 33 + 24 + jj];
      float fg = sigf(zf), ig = sigf(zi), gg = tanh_fast(zg), og = sigf(zo);
      float cnew = fg * creg[it] + ig * gg;
      float hnew = og * tanh_fast(cnew);
      creg[it] = cnew;
      hnew_s[it] = hnew; cnew_s[it] = cnew; bidx[it] = b;
      houtbuf[b * 8 + jj] = f2bf(hnew);
    }
    // ---- publish this wave's 16x8 slice (coherent stores, scalar u32 inputs) + flag ----
    if (lane < 16) {
      const u32* hv = (const u32*)&houtbuf[(v * 16 + lane) * 8];
      u32 v0 = hv[0], v1 = hv[1], v2 = hv[2], v3 = hv[3];
      size_t ci = (((size_t)v * 16 + (w >> 2)) * 4 + (w & 3)) * 16 + lane;
      void* dst = hnxt + ci * 16;
      asm volatile(
          "global_store_dword %0, %1, off sc0 sc1\n\t"
          "global_store_dword %0, %2, off offset:4 sc0 sc1\n\t"
          "global_store_dword %0, %3, off offset:8 sc0 sc1\n\t"
          "global_store_dword %0, %4, off offset:12 sc0 sc1"
          :: "v"(dst), "v"(v0), "v"(v1), "v"(v2), "v"(v3) : "memory");
    }
    asm volatile("s_waitcnt vmcnt(0)" ::: "memory");
    if (lane == 0) {
      u32 tag = (u32)(t + 1);
      u32* fdst = flags + (w * 4 + v);
      asm volatile("global_store_dword %0, %1, off sc0 sc1" :: "v"(fdst), "v"(tag) : "memory");
    }
    // ---- out stores (off critical path) ----
#pragma unroll
    for (int it = 0; it < 2; ++it) {
      int item = it * 64 + lane, jj = item & 7, b = bidx[it];
      size_t oi = ((size_t)t * 64 + b) * 512 + w * 8 + jj;
      if (mode) ((u16*)out)[oi] = f2bf(hnew_s[it]); else ((float*)out)[oi] = hnew_s[it];
      if (t == T_STEPS - 1) {
        size_t hx = NOUT_H + (size_t)b * 512 + w * 8 + jj;
        if (mode) { ((u16*)out)[hx] = f2bf(hnew_s[it]); ((u16*)out)[hx + 32768] = f2bf(cnew_s[it]); }
        else      { ((float*)out)[hx] = hnew_s[it]; ((float*)out)[hx + 32768] = cnew_s[it]; }
      }
    }
  }
}

extern "C" void kernel_launch(void* const* d_in, const int* in_sizes, int n_in,
                              void* d_out, int out_size, void* d_ws, size_t ws_size,
                              hipStream_t stream) {
  const void* X = d_in[0];
  u32* ws = (u32*)d_ws;
  int xwf32 = (ws_size >= (size_t)(WS_XW + 268435456ull + 1024ull)) ? 1 : 0;

  k_detect<<<1, 256, 0, stream>>>((const u32*)X, ws);
  k_convx<<<16384, 256, 0, stream>>>(ws, X, (u16*)((char*)d_ws + WS_XC));
  k_prepw<<<1024, 256, 0, stream>>>(ws, d_in[1], d_in[3], d_in[5], d_in[7],
                                    d_in[2], d_in[4], d_in[6], d_in[8]);
  k_xw<<<8192, 256, 0, stream>>>(ws, X, xwf32);
  k_rec<<<64, 256, 0, stream>>>(ws, d_out, xwf32);
}